// Round 1
// baseline (2906.503 us; speedup 1.0000x reference)
//
#include <hip/hip_runtime.h>

#define D_FEAT 128

// --- 1. degree count: one thread per edge, two int atomics ---
__global__ void degree_kernel(const int* __restrict__ src, const int* __restrict__ dst,
                              int* __restrict__ deg_o, int* __restrict__ deg_i, int n_edges) {
    int e = blockIdx.x * blockDim.x + threadIdx.x;
    if (e < n_edges) {
        atomicAdd(&deg_o[src[e]], 1);
        atomicAdd(&deg_i[dst[e]], 1);
    }
}

// --- 2. deg (int) -> rsqrt(max(deg,1)) (float), in place (same 4B slot per thread) ---
__global__ void norm_kernel(int* __restrict__ deg, int n) {
    int i = blockIdx.x * blockDim.x + threadIdx.x;
    if (i < n) {
        int d = deg[i];
        if (d < 1) d = 1;
        float v = rsqrtf((float)d);
        ((float*)deg)[i] = v;
    }
}

// --- 3. scatter: 32 threads per edge, each handles one float4 of the 128 feats ---
__global__ void scatter_kernel(const float* __restrict__ feat,
                               const int* __restrict__ src, const int* __restrict__ dst,
                               const float* __restrict__ norm_l,
                               float* __restrict__ out, int n_edges) {
    long long gid = (long long)blockIdx.x * blockDim.x + threadIdx.x;
    int e    = (int)(gid >> 5);
    int lane = (int)(gid & 31);
    if (e >= n_edges) return;
    int s = src[e];
    int d = dst[e];
    float nl = norm_l[s];
    const float4 v = ((const float4*)(feat + (size_t)s * D_FEAT))[lane];
    float* op = out + (size_t)d * D_FEAT + (size_t)lane * 4;
    atomicAdd(op + 0, v.x * nl);
    atomicAdd(op + 1, v.y * nl);
    atomicAdd(op + 2, v.z * nl);
    atomicAdd(op + 3, v.w * nl);
}

// --- 4. final in-degree normalization: 32 threads per node, float4 ---
__global__ void scale_kernel(float* __restrict__ out, const float* __restrict__ norm_r,
                             int n_nodes) {
    long long gid = (long long)blockIdx.x * blockDim.x + threadIdx.x;
    int n    = (int)(gid >> 5);
    int lane = (int)(gid & 31);
    if (n >= n_nodes) return;
    float nr = norm_r[n];
    float4* op = (float4*)(out + (size_t)n * D_FEAT) + lane;
    float4 v = *op;
    v.x *= nr; v.y *= nr; v.z *= nr; v.w *= nr;
    *op = v;
}

extern "C" void kernel_launch(void* const* d_in, const int* in_sizes, int n_in,
                              void* d_out, int out_size, void* d_ws, size_t ws_size,
                              hipStream_t stream) {
    const float* feat = (const float*)d_in[0];
    const int*   src  = (const int*)d_in[1];
    const int*   dst  = (const int*)d_in[2];
    float* out = (float*)d_out;

    const int n_nodes = in_sizes[0] / D_FEAT;   // 100000
    const int n_edges = in_sizes[1];            // 1600000

    // ws layout: deg_o int[n_nodes] | deg_i int[n_nodes]  (later reused as float norms)
    int* deg_o = (int*)d_ws;
    int* deg_i = deg_o + n_nodes;

    // zero accumulators (d_ws / d_out are poisoned before every timed call)
    hipMemsetAsync(d_ws, 0, (size_t)2 * n_nodes * sizeof(int), stream);
    hipMemsetAsync(d_out, 0, (size_t)out_size * sizeof(float), stream);

    // 1. degrees
    {
        int threads = 256;
        int blocks = (n_edges + threads - 1) / threads;
        degree_kernel<<<blocks, threads, 0, stream>>>(src, dst, deg_o, deg_i, n_edges);
    }
    // 2. norms (both arrays at once: 2*n_nodes contiguous ints)
    {
        int total = 2 * n_nodes;
        int threads = 256;
        int blocks = (total + threads - 1) / threads;
        norm_kernel<<<blocks, threads, 0, stream>>>(deg_o, total);
    }
    // 3. scatter-add
    {
        long long total = (long long)n_edges * 32;
        int threads = 256;
        long long blocks = (total + threads - 1) / threads;
        scatter_kernel<<<(int)blocks, threads, 0, stream>>>(feat, src, dst,
                                                            (const float*)deg_o, out, n_edges);
    }
    // 4. in-degree scale
    {
        long long total = (long long)n_nodes * 32;
        int threads = 256;
        long long blocks = (total + threads - 1) / threads;
        scale_kernel<<<(int)blocks, threads, 0, stream>>>(out, (const float*)deg_i, n_nodes);
    }
}

// Round 2
// 460.394 us; speedup vs baseline: 6.3131x; 6.3131x over previous
//
#include <hip/hip_runtime.h>

#define D_FEAT 128

// --- 1. degree count: one thread per edge, two int atomics ---
__global__ void degree_kernel(const int* __restrict__ src, const int* __restrict__ dst,
                              int* __restrict__ deg_o, int* __restrict__ deg_i, int n_edges) {
    int e = blockIdx.x * blockDim.x + threadIdx.x;
    if (e < n_edges) {
        atomicAdd(&deg_o[src[e]], 1);
        atomicAdd(&deg_i[dst[e]], 1);
    }
}

// --- scan step 1: per-1024-chunk block sums ---
__global__ void block_reduce_kernel(const int* __restrict__ deg, int* __restrict__ bsums, int n) {
    __shared__ int lds[256];
    int t = threadIdx.x;
    int base = blockIdx.x * 1024;
    int s = 0;
    for (int i = t; i < 1024; i += 256) {
        int idx = base + i;
        if (idx < n) s += deg[idx];
    }
    lds[t] = s;
    __syncthreads();
    for (int off = 128; off > 0; off >>= 1) {
        if (t < off) lds[t] += lds[t + off];
        __syncthreads();
    }
    if (t == 0) bsums[blockIdx.x] = lds[0];
}

// --- scan step 2: single-block exclusive scan of block sums (nb <= 256) ---
__global__ void scan_sums_kernel(int* __restrict__ bsums, int nb) {
    __shared__ int tmp[256];
    int t = threadIdx.x;
    int v = (t < nb) ? bsums[t] : 0;
    tmp[t] = v;
    __syncthreads();
    for (int off = 1; off < 256; off <<= 1) {
        int x = (t >= off) ? tmp[t - off] : 0;
        __syncthreads();
        tmp[t] += x;
        __syncthreads();
    }
    if (t < nb) bsums[t] = tmp[t] - v;  // exclusive
}

// --- scan step 3: final exclusive scan, writes row_ptr and cursor copy ---
__global__ void scan_final_kernel(const int* __restrict__ deg, const int* __restrict__ bsums,
                                  int* __restrict__ row_ptr, int* __restrict__ cursor,
                                  int n, int n_edges) {
    __shared__ int tmp[256];
    int t = threadIdx.x;
    int base = blockIdx.x * 1024 + t * 4;
    int v0 = 0, v1 = 0, v2 = 0, v3 = 0;
    if (base + 0 < n) v0 = deg[base + 0];
    if (base + 1 < n) v1 = deg[base + 1];
    if (base + 2 < n) v2 = deg[base + 2];
    if (base + 3 < n) v3 = deg[base + 3];
    int s = v0 + v1 + v2 + v3;
    tmp[t] = s;
    __syncthreads();
    for (int off = 1; off < 256; off <<= 1) {
        int x = (t >= off) ? tmp[t - off] : 0;
        __syncthreads();
        tmp[t] += x;
        __syncthreads();
    }
    int run = bsums[blockIdx.x] + tmp[t] - s;  // exclusive prefix at base
    int vv[4] = {v0, v1, v2, v3};
    for (int j = 0; j < 4; j++) {
        int idx = base + j;
        if (idx < n) { row_ptr[idx] = run; cursor[idx] = run; }
        run += vv[j];
    }
    if (blockIdx.x == 0 && t == 0) row_ptr[n] = n_edges;
}

// --- 2b. deg (int) -> rsqrt(max(deg,1)) (float), in place ---
__global__ void norm_kernel(int* __restrict__ deg, int n) {
    int i = blockIdx.x * blockDim.x + threadIdx.x;
    if (i < n) {
        int d = deg[i];
        if (d < 1) d = 1;
        ((float*)deg)[i] = rsqrtf((float)d);
    }
}

// --- 3. fill CSR: scatter src index into dst-sorted slot (int atomics only) ---
__global__ void fill_kernel(const int* __restrict__ src, const int* __restrict__ dst,
                            int* __restrict__ cursor, int* __restrict__ src_sorted, int n_edges) {
    int e = blockIdx.x * blockDim.x + threadIdx.x;
    if (e < n_edges) {
        int pos = atomicAdd(&cursor[dst[e]], 1);
        src_sorted[pos] = src[e];
    }
}

// --- 4. pull-aggregate: 32 threads per node, lane owns one float4 of 128 feats ---
__global__ __launch_bounds__(256) void pull_kernel(
        const float* __restrict__ feat, const int* __restrict__ src_sorted,
        const int* __restrict__ row_ptr, const float* __restrict__ norm_l,
        const float* __restrict__ norm_r, float* __restrict__ out, int n_nodes) {
    long long gid = (long long)blockIdx.x * blockDim.x + threadIdx.x;
    int node = (int)(gid >> 5);
    int lane = (int)(gid & 31);
    if (node >= n_nodes) return;
    int beg = row_ptr[node];
    int end = row_ptr[node + 1];
    float4 acc = make_float4(0.f, 0.f, 0.f, 0.f);
    for (int k = beg; k < end; k++) {
        int s = src_sorted[k];
        float nl = norm_l[s];
        float4 v = ((const float4*)(feat + (size_t)s * D_FEAT))[lane];
        acc.x += v.x * nl;
        acc.y += v.y * nl;
        acc.z += v.z * nl;
        acc.w += v.w * nl;
    }
    float nr = norm_r[node];
    acc.x *= nr; acc.y *= nr; acc.z *= nr; acc.w *= nr;
    ((float4*)(out + (size_t)node * D_FEAT))[lane] = acc;
}

extern "C" void kernel_launch(void* const* d_in, const int* in_sizes, int n_in,
                              void* d_out, int out_size, void* d_ws, size_t ws_size,
                              hipStream_t stream) {
    const float* feat = (const float*)d_in[0];
    const int*   src  = (const int*)d_in[1];
    const int*   dst  = (const int*)d_in[2];
    float* out = (float*)d_out;

    const int n_nodes = in_sizes[0] / D_FEAT;   // 100000
    const int n_edges = in_sizes[1];            // 1600000

    const int NB = (n_nodes + 1023) / 1024;     // 98 scan blocks

    // ws layout (ints): deg_o/norm_l [n] | deg_i/norm_r [n] | row_ptr [n+1] |
    //                   cursor [n] | bsums [NB] | src_sorted [n_edges]
    int* deg_o      = (int*)d_ws;
    int* deg_i      = deg_o + n_nodes;
    int* row_ptr    = deg_i + n_nodes;
    int* cursor     = row_ptr + (n_nodes + 1);
    int* bsums      = cursor + n_nodes;
    int* src_sorted = bsums + NB;

    // zero only the degree counters (ws is poisoned before every timed call)
    hipMemsetAsync(d_ws, 0, (size_t)2 * n_nodes * sizeof(int), stream);

    // 1. degrees
    degree_kernel<<<(n_edges + 255) / 256, 256, 0, stream>>>(src, dst, deg_o, deg_i, n_edges);

    // 2. exclusive scan of deg_i -> row_ptr (+cursor copy)
    block_reduce_kernel<<<NB, 256, 0, stream>>>(deg_i, bsums, n_nodes);
    scan_sums_kernel<<<1, 256, 0, stream>>>(bsums, NB);
    scan_final_kernel<<<NB, 256, 0, stream>>>(deg_i, bsums, row_ptr, cursor, n_nodes, n_edges);

    // 2b. degrees -> rsqrt norms (in place; deg_i ints no longer needed)
    norm_kernel<<<(2 * n_nodes + 255) / 256, 256, 0, stream>>>(deg_o, 2 * n_nodes);

    // 3. CSR fill (dst-sorted src indices)
    fill_kernel<<<(n_edges + 255) / 256, 256, 0, stream>>>(src, dst, cursor, src_sorted, n_edges);

    // 4. pull aggregation (no atomics), fused final scale
    {
        long long total = (long long)n_nodes * 32;
        int blocks = (int)((total + 255) / 256);
        pull_kernel<<<blocks, 256, 0, stream>>>(feat, src_sorted, row_ptr,
                                                (const float*)deg_o, (const float*)deg_i,
                                                out, n_nodes);
    }
}